// Round 6
// baseline (59.440 us; speedup 1.0000x reference)
//
#include <hip/hip_runtime.h>
#include <hip/hip_fp16.h>

typedef _Float16 half8 __attribute__((ext_vector_type(8)));
typedef float float4v __attribute__((ext_vector_type(4)));

#define E_DIM 300
#define KP 320               // padded K (10 MFMA k-steps of 32)
#define B_ 32
#define NROW_CDD 3200        // 32*5*20
#define NROW_HIS 32000       // 32*50*20
#define NCHUNK 25            // 2 h per chunk, 40 his rows
#define LDST 656             // LDS row stride bytes: (r*164+g*4)%32 -> 2-way max (free)

// ---------------- Kernel 1: gather + l2-normalize -> fp16 rows (K padded to 320) --------
__global__ __launch_bounds__(256) void gather_norm(const int* __restrict__ cand,
                                                   const int* __restrict__ clk,
                                                   const float* __restrict__ emb,
                                                   _Float16* __restrict__ outH)
{
    int row  = blockIdx.x * 4 + (threadIdx.x >> 6);
    int lane = threadIdx.x & 63;
    int tok = (row < NROW_CDD) ? cand[row] : clk[row - NROW_CDD];
    const float* e = emb + (long)tok * E_DIM;
    float v[5];
    float ss = 0.f;
#pragma unroll
    for (int j = 0; j < 5; ++j) {
        int idx = lane + j * 64;
        float x = (idx < E_DIM) ? e[idx] : 0.f;
        v[j] = x;
        ss += x * x;
    }
#pragma unroll
    for (int off = 32; off; off >>= 1) ss += __shfl_xor(ss, off);
    float scale = 1.0f / fmaxf(sqrtf(ss), 1e-12f);
    _Float16* o = outH + (long)row * KP;
#pragma unroll
    for (int j = 0; j < 5; ++j) {
        int idx = lane + j * 64;
        o[idx] = (_Float16)((idx < E_DIM) ? v[j] * scale : 0.f);
    }
}

// ---------------- Kernel 2: fused sim-GEMM + gaussian pooling ---------------------------
// grid (25, 32), 256 threads. A+B reg-staged to LDS with ALL global loads issued up-front
// (MLP fix: ~90 KB in flight/block instead of dependent in-loop fragment loads).
// LDS ~101 KB -> 1 block/CU.
__global__ __launch_bounds__(256, 1) void knrm_fused(const _Float16* __restrict__ wsH,
                                                     const float* __restrict__ cpad,
                                                     const float* __restrict__ hpad,
                                                     const float* __restrict__ ltr_w,
                                                     float* __restrict__ partial)
{
    __shared__ __align__(16) char Abuf[100 * LDST];     // 65600
    __shared__ __align__(16) char Bbuf[40 * LDST];      // 26240
    __shared__ _Float16 simH[100 * 42];                 // 8400
    __shared__ float hpS[40];
    __shared__ float wvS[40];
    __shared__ float svals[200];

    int b = blockIdx.y, chunk = blockIdx.x;
    int tid = threadIdx.x;
    int wave = tid >> 6, lane = tid & 63;
    int g = lane >> 4, r16 = lane & 15;

    // ---- stage: issue ALL global loads first (A: 64000 B, B: 25600 B, contiguous) ----
    const uint4* gA4 = (const uint4*)(wsH + (size_t)b * 100 * KP);                       // 4000 chunks
    const uint4* gB4 = (const uint4*)(wsH + (size_t)(NROW_CDD + b * 1000 + chunk * 40) * KP); // 1600

    uint4 av[15], at, bv[6], bt;
#pragma unroll
    for (int j = 0; j < 15; ++j) av[j] = gA4[tid + 256 * j];
#pragma unroll
    for (int j = 0; j < 6; ++j) bv[j] = gB4[tid + 256 * j];
    if (tid < 160) at = gA4[3840 + tid];
    if (tid < 64)  bt = gB4[1536 + tid];
    if (tid < 40) {
        hpS[tid] = hpad[b * 1000 + chunk * 40 + tid];
        wvS[tid] = ltr_w[chunk * 40 + tid];
    }

    // ---- LDS writes (row-major, stride 656 B: conflict-free) ----
#pragma unroll
    for (int j = 0; j < 15; ++j) {
        int c = tid + 256 * j; int r = c / 40;
        *(uint4*)(Abuf + r * LDST + (c - r * 40) * 16) = av[j];
    }
    if (tid < 160) {
        int c = 3840 + tid; int r = c / 40;
        *(uint4*)(Abuf + r * LDST + (c - r * 40) * 16) = at;
    }
#pragma unroll
    for (int j = 0; j < 6; ++j) {
        int c = tid + 256 * j; int r = c / 40;
        *(uint4*)(Bbuf + r * LDST + (c - r * 40) * 16) = bv[j];
    }
    if (tid < 64) {
        int c = 1536 + tid; int r = c / 40;
        *(uint4*)(Bbuf + r * LDST + (c - r * 40) * 16) = bt;
    }
    __syncthreads();

    // ---- Phase 1: 100x40 sim tile via MFMA, both operands from LDS ----
    float4v acc[2][3];
#pragma unroll
    for (int mi = 0; mi < 2; ++mi)
#pragma unroll
        for (int n = 0; n < 3; ++n) acc[mi][n] = (float4v){0.f, 0.f, 0.f, 0.f};

#pragma unroll 2
    for (int k = 0; k < 10; ++k) {
        half8 bf[3];
#pragma unroll
        for (int n = 0; n < 3; ++n)
            bf[n] = *(const half8*)(Bbuf + (n * 16 + r16) * LDST + k * 64 + g * 16);
#pragma unroll
        for (int mi = 0; mi < 2; ++mi) {
            int m = wave * 2 + mi;
            if (m < 7) {
                int rA = m * 16 + r16; if (rA > 99) rA = 99;
                half8 af = *(const half8*)(Abuf + rA * LDST + k * 64 + g * 16);
#pragma unroll
                for (int n = 0; n < 3; ++n)
                    acc[mi][n] = __builtin_amdgcn_mfma_f32_16x16x32_f16(af, bf[n], acc[mi][n], 0, 0, 0);
            }
        }
    }
    // C/D layout (m89-verified): col = lane&15 (B-row), row = (lane>>4)*4+j (A-row)
#pragma unroll
    for (int mi = 0; mi < 2; ++mi) {
        int m = wave * 2 + mi;
        if (m < 7) {
#pragma unroll
            for (int n = 0; n < 3; ++n) {
                int col = n * 16 + r16;
                if (col < 40) {
#pragma unroll
                    for (int j = 0; j < 4; ++j) {
                        int row = m * 16 + g * 4 + j;
                        if (row < 100) simH[row * 42 + col] = (_Float16)acc[mi][n][j];
                    }
                }
            }
        }
    }
    __syncthreads();

    // ---- Phase 2: gaussian kernels + log pooling (fast intrinsics, psum[20] static) ----
    int unit_h = tid / 100;          // 0 or 1 (for tid<200)
    int row = tid - unit_h * 100;

    if (tid < 200) {
        float psum[20];
#pragma unroll
        for (int k = 0; k < 20; ++k) psum[k] = 0.f;

        const _Float16* sp = simH + row * 42 + unit_h * 20;
        const float* mp = hpS + unit_h * 20;
#pragma unroll 4
        for (int t = 0; t < 20; ++t) {
            float s  = (float)sp[t];
            float mm = mp[t];
            float a  = -50.0f * s * s;     // -1/(2*0.1^2) = -50
#pragma unroll
            for (int k = 0; k < 19; ++k) {
                const float mu = -0.9f + 0.1f * (float)k;
                const float bk = 100.0f * mu;
                const float ck = -50.0f * mu * mu;
                float arg = fmaf(bk, s, a + ck);   // -50(s-mu)^2
                psum[k] = fmaf(__expf(arg), mm, psum[k]);
            }
            float d = s - 1.0f;
            psum[19] = fmaf(__expf(-500000.0f * d * d), mm, psum[19]);
        }
        float val = 0.f;
#pragma unroll
        for (int k = 0; k < 20; ++k)
            val += __logf(fmaxf(psum[k], 1e-10f)) * wvS[unit_h * 20 + k];
        val *= 0.01f * cpad[b * 100 + row];
        svals[row * 2 + unit_h] = val;
    }
    __syncthreads();

    // ---- per-candidate partial for this chunk ----
    if (tid < 5) {
        float ssum = 0.f;
#pragma unroll
        for (int i = 0; i < 40; ++i) ssum += svals[tid * 40 + i];
        partial[(b * 5 + tid) * NCHUNK + chunk] = ssum;
    }
}

// ---------------- Kernel 3: sum chunks + bias + log_softmax over C=5 --------------------
__global__ __launch_bounds__(64) void finalize(const float* __restrict__ partial,
                                               const float* __restrict__ ltr_b,
                                               float* __restrict__ out)
{
    int b = blockIdx.x;
    int tid = threadIdx.x;
    __shared__ float sc[5];
    if (tid < 5) {
        float a = ltr_b[0];
        const float* pp = partial + (b * 5 + tid) * NCHUNK;
#pragma unroll
        for (int ch = 0; ch < NCHUNK; ++ch) a += pp[ch];
        sc[tid] = a;
    }
    __syncthreads();
    if (tid < 5) {
        float m = fmaxf(fmaxf(fmaxf(sc[0], sc[1]), fmaxf(sc[2], sc[3])), sc[4]);
        float sum = 0.f;
#pragma unroll
        for (int i = 0; i < 5; ++i) sum += __expf(sc[i] - m);
        out[b * 5 + tid] = sc[tid] - m - __logf(sum);
    }
}

extern "C" void kernel_launch(void* const* d_in, const int* in_sizes, int n_in,
                              void* d_out, int out_size, void* d_ws, size_t ws_size,
                              hipStream_t stream)
{
    const int*   cand = (const int*)d_in[0];
    const int*   clk  = (const int*)d_in[1];
    const float* cpad = (const float*)d_in[2];
    const float* hpad = (const float*)d_in[3];
    const float* emb  = (const float*)d_in[4];
    const float* lw   = (const float*)d_in[5];
    const float* lb   = (const float*)d_in[6];
    float* out = (float*)d_out;

    _Float16* wsH  = (_Float16*)d_ws;                                                    // 22.528 MB
    float* partial = (float*)((char*)d_ws + (size_t)(NROW_CDD + NROW_HIS) * KP * 2);     // 16 KB

    hipLaunchKernelGGL(gather_norm, dim3((NROW_CDD + NROW_HIS) / 4), dim3(256), 0, stream,
                       cand, clk, emb, wsH);
    hipLaunchKernelGGL(knrm_fused, dim3(NCHUNK, B_), dim3(256), 0, stream,
                       wsH, cpad, hpad, lw, partial);
    hipLaunchKernelGGL(finalize, dim3(B_), dim3(64), 0, stream, partial, lb, out);
}

// Round 7
// 55.584 us; speedup vs baseline: 1.0694x; 1.0694x over previous
//
#include <hip/hip_runtime.h>
#include <hip/hip_fp16.h>

typedef _Float16 half8 __attribute__((ext_vector_type(8)));
typedef _Float16 half4v __attribute__((ext_vector_type(4)));
typedef _Float16 half2v __attribute__((ext_vector_type(2)));
typedef float float4v __attribute__((ext_vector_type(4)));

#define E_DIM 300
#define KP 320               // padded K (10 MFMA k-steps of 32)
#define B_ 32
#define NROW_CDD 3200        // 32*5*20
#define NROW_HIS 32000       // 32*50*20
#define LDSTB 656            // B-tile LDS row stride (bytes)

// ---------------- Kernel 1: gather + l2-normalize -> fp16 rows (K padded to 320) --------
__global__ __launch_bounds__(256) void gather_norm(const int* __restrict__ cand,
                                                   const int* __restrict__ clk,
                                                   const float* __restrict__ emb,
                                                   _Float16* __restrict__ outH)
{
    int row  = blockIdx.x * 4 + (threadIdx.x >> 6);
    int lane = threadIdx.x & 63;
    int tok = (row < NROW_CDD) ? cand[row] : clk[row - NROW_CDD];
    const float* e = emb + (long)tok * E_DIM;
    float v[5];
    float ss = 0.f;
#pragma unroll
    for (int j = 0; j < 5; ++j) {
        int idx = lane + j * 64;
        float x = (idx < E_DIM) ? e[idx] : 0.f;
        v[j] = x;
        ss += x * x;
    }
#pragma unroll
    for (int off = 32; off; off >>= 1) ss += __shfl_xor(ss, off);
    float scale = 1.0f / fmaxf(sqrtf(ss), 1e-12f);
    _Float16* o = outH + (long)row * KP;
#pragma unroll
    for (int j = 0; j < 5; ++j) {
        int idx = lane + j * 64;
        o[idx] = (_Float16)((idx < E_DIM) ? v[j] * scale : 0.f);
    }
}

// ---------------- Kernel 2: sim GEMM -> fp16 sim matrix [b][100][1000] -----------------
// grid (16 ntiles, 32 b), 256 threads, LDS ~68 KB -> 2 blocks/CU (8 waves/CU).
__global__ __launch_bounds__(256) void sim_gemm(const _Float16* __restrict__ wsH,
                                                _Float16* __restrict__ simW)
{
    __shared__ __align__(16) char Bs[64 * LDSTB];   // 41984 B
    __shared__ float simT[100 * 66];                // 26400 B

    int b = blockIdx.y, ntile = blockIdx.x;
    int tid = threadIdx.x;
    int wave = tid >> 6, lane = tid & 63;
    int g = lane >> 4, r16 = lane & 15;

    const char* gA = (const char*)(wsH + (size_t)b * 100 * KP);
    const char* gB = (const char*)(wsH + (size_t)(NROW_CDD + b * 1000) * KP);

    // stage B tile: 64 his rows x 640 B, coalesced
    for (int u = tid; u < 2560; u += 256) {
        int r = u / 40, c = u - r * 40;
        int gr = ntile * 64 + r; if (gr > 999) gr = 999;
        *(uint4*)(Bs + r * LDSTB + c * 16) = *(const uint4*)(gB + (size_t)gr * 640 + c * 16);
    }
    __syncthreads();

    float4v acc[7];
#pragma unroll
    for (int m = 0; m < 7; ++m) acc[m] = (float4v){0.f, 0.f, 0.f, 0.f};

#pragma unroll 2
    for (int k = 0; k < 10; ++k) {
        half8 bf = *(const half8*)(Bs + (wave * 16 + r16) * LDSTB + k * 64 + g * 16);
#pragma unroll
        for (int m = 0; m < 7; ++m) {
            int rA = m * 16 + r16; if (rA > 99) rA = 99;
            half8 af = *(const half8*)(gA + (size_t)rA * 640 + k * 64 + g * 16);
            acc[m] = __builtin_amdgcn_mfma_f32_16x16x32_f16(af, bf, acc[m], 0, 0, 0);
        }
    }

    // C/D layout (validated r1-r6): col = lane&15 (B-row), row = (lane>>4)*4+j (A-row)
    int lcol = wave * 16 + r16;
#pragma unroll
    for (int m = 0; m < 7; ++m) {
#pragma unroll
        for (int j = 0; j < 4; ++j) {
            int r = m * 16 + g * 4 + j;
            if (r < 100) simT[r * 66 + lcol] = acc[m][j];
        }
    }
    __syncthreads();

    // coalesced fp16 write-out (pairs -> 4 B stores)
    for (int u = tid; u < 3200; u += 256) {
        int r = u >> 5, cp = u & 31;
        int gcol = ntile * 64 + cp * 2;
        if (gcol < 999) {
            half2v hv = { (_Float16)simT[r * 66 + cp * 2], (_Float16)simT[r * 66 + cp * 2 + 1] };
            *(half2v*)(simW + (size_t)(b * 100 + r) * 1000 + gcol) = hv;
        }
    }
}

// ---------------- Kernel 3: gaussian kernels + log pooling, one block per sim row -------
// grid 3200, 256 threads (250 active: h=tid%50, kq=tid/50, 4 k's each). LDS 12.6 KB.
__global__ __launch_bounds__(256) void knrm_pool(const _Float16* __restrict__ simW,
                                                 const float* __restrict__ cpad,
                                                 const float* __restrict__ hpad,
                                                 const float* __restrict__ ltr_w,
                                                 float* __restrict__ rowsum)
{
    __shared__ float sS[50 * 21];
    __shared__ float mS[50 * 21];
    __shared__ float wS[1000];
    __shared__ float part[4];

    int row = blockIdx.x;            // (b*5+c)*20 + s
    int b = row / 100;
    int tid = threadIdx.x;

    if (tid < 250) {
        int p = tid * 4;
        half4v hv = *(const half4v*)(simW + (size_t)row * 1000 + p);
        float4v mv = *(const float4v*)(hpad + (size_t)b * 1000 + p);
        *(float4v*)&wS[p] = *(const float4v*)(ltr_w + p);
#pragma unroll
        for (int q = 0; q < 4; ++q) {
            int pq = p + q, h = pq / 20, t = pq - h * 20;
            sS[h * 21 + t] = (float)hv[q];
            mS[h * 21 + t] = mv[q];
        }
    }
    __syncthreads();

    float val = 0.f;
    if (tid < 250) {
        int h = tid % 50, kq = tid / 50;     // kq 0..4, k = kq*4+j
        // hoist per-j quadratic constants: -50(s-mu)^2 = ((-50 s + 100mu) s - 50mu^2)
        float bj[4], cj[4];
        bool is19[4];
#pragma unroll
        for (int j = 0; j < 4; ++j) {
            float mu = -0.9f + 0.1f * (float)(kq * 4 + j);
            bj[j] = 100.0f * mu;
            cj[j] = -50.0f * mu * mu;
            is19[j] = (kq * 4 + j) == 19;
        }
        float psum0 = 0.f, psum1 = 0.f, psum2 = 0.f, psum3 = 0.f;
        const float* sp = sS + h * 21;
        const float* mp = mS + h * 21;
#pragma unroll 4
        for (int t = 0; t < 20; ++t) {
            float s  = sp[t];
            float mm = mp[t];
            float d  = s - 1.0f;
            float arg19 = -500000.0f * d * d;
            float a0 = is19[0] ? arg19 : fmaf(fmaf(-50.0f, s, bj[0]), s, cj[0]);
            float a1 = is19[1] ? arg19 : fmaf(fmaf(-50.0f, s, bj[1]), s, cj[1]);
            float a2 = is19[2] ? arg19 : fmaf(fmaf(-50.0f, s, bj[2]), s, cj[2]);
            float a3 = is19[3] ? arg19 : fmaf(fmaf(-50.0f, s, bj[3]), s, cj[3]);
            psum0 = fmaf(__expf(a0), mm, psum0);
            psum1 = fmaf(__expf(a1), mm, psum1);
            psum2 = fmaf(__expf(a2), mm, psum2);
            psum3 = fmaf(__expf(a3), mm, psum3);
        }
        const float* wp = wS + h * 20 + kq * 4;
        val  = __logf(fmaxf(psum0, 1e-10f)) * wp[0];
        val += __logf(fmaxf(psum1, 1e-10f)) * wp[1];
        val += __logf(fmaxf(psum2, 1e-10f)) * wp[2];
        val += __logf(fmaxf(psum3, 1e-10f)) * wp[3];
    }
#pragma unroll
    for (int off = 32; off; off >>= 1) val += __shfl_down(val, off);
    int wave = tid >> 6, lane = tid & 63;
    if (lane == 0) part[wave] = val;
    __syncthreads();
    if (tid == 0)
        rowsum[row] = (part[0] + part[1] + part[2] + part[3]) * 0.01f * cpad[row];
}

// ---------------- Kernel 4: sum rows per (b,c) + bias + log_softmax over C=5 ------------
__global__ __launch_bounds__(64) void finalize(const float* __restrict__ rowsum,
                                               const float* __restrict__ ltr_b,
                                               float* __restrict__ out)
{
    int b = blockIdx.x;
    int tid = threadIdx.x;
    __shared__ float sc[5];
    if (tid < 5) {
        float a = ltr_b[0];
        const float* rp = rowsum + (b * 5 + tid) * 20;
#pragma unroll
        for (int s = 0; s < 20; ++s) a += rp[s];
        sc[tid] = a;
    }
    __syncthreads();
    if (tid < 5) {
        float m = fmaxf(fmaxf(fmaxf(sc[0], sc[1]), fmaxf(sc[2], sc[3])), sc[4]);
        float sum = 0.f;
#pragma unroll
        for (int i = 0; i < 5; ++i) sum += __expf(sc[i] - m);
        out[b * 5 + tid] = sc[tid] - m - __logf(sum);
    }
}

extern "C" void kernel_launch(void* const* d_in, const int* in_sizes, int n_in,
                              void* d_out, int out_size, void* d_ws, size_t ws_size,
                              hipStream_t stream)
{
    const int*   cand = (const int*)d_in[0];
    const int*   clk  = (const int*)d_in[1];
    const float* cpad = (const float*)d_in[2];
    const float* hpad = (const float*)d_in[3];
    const float* emb  = (const float*)d_in[4];
    const float* lw   = (const float*)d_in[5];
    const float* lb   = (const float*)d_in[6];
    float* out = (float*)d_out;

    _Float16* wsH  = (_Float16*)d_ws;                                                   // 22.528 MB
    _Float16* simW = (_Float16*)((char*)d_ws + (size_t)(NROW_CDD + NROW_HIS) * KP * 2); // 6.4 MB
    float* rowsum  = (float*)((char*)simW + (size_t)B_ * 100 * 1000 * 2);               // 12.8 KB

    hipLaunchKernelGGL(gather_norm, dim3((NROW_CDD + NROW_HIS) / 4), dim3(256), 0, stream,
                       cand, clk, emb, wsH);
    hipLaunchKernelGGL(sim_gemm, dim3(16, B_), dim3(256), 0, stream, wsH, simW);
    hipLaunchKernelGGL(knrm_pool, dim3(NROW_CDD), dim3(256), 0, stream,
                       simW, cpad, hpad, lw, rowsum);
    hipLaunchKernelGGL(finalize, dim3(B_), dim3(64), 0, stream, rowsum, lb, out);
}

// Round 8
// 47.889 us; speedup vs baseline: 1.2412x; 1.1607x over previous
//
#include <hip/hip_runtime.h>
#include <hip/hip_fp16.h>

typedef _Float16 half8 __attribute__((ext_vector_type(8)));
typedef _Float16 half4v __attribute__((ext_vector_type(4)));
typedef float float4v __attribute__((ext_vector_type(4)));

#define E_DIM 300
#define KP 320               // padded K (10 MFMA k-steps of 32)
#define B_ 32
#define NROW_CDD 3200        // 32*5*20
#define NROW_HIS 32000       // 32*50*20
#define LDSTB 656            // LDS row stride (bytes); + XOR swizzle -> 2-way max (free)

// ---------------- Kernel 1: gather + l2-normalize -> fp16 rows (K padded to 320) --------
__global__ __launch_bounds__(256) void gather_norm(const int* __restrict__ cand,
                                                   const int* __restrict__ clk,
                                                   const float* __restrict__ emb,
                                                   _Float16* __restrict__ outH)
{
    int row  = blockIdx.x * 4 + (threadIdx.x >> 6);
    int lane = threadIdx.x & 63;
    int tok = (row < NROW_CDD) ? cand[row] : clk[row - NROW_CDD];
    const float* e = emb + (long)tok * E_DIM;
    float v[5];
    float ss = 0.f;
#pragma unroll
    for (int j = 0; j < 5; ++j) {
        int idx = lane + j * 64;
        float x = (idx < E_DIM) ? e[idx] : 0.f;
        v[j] = x;
        ss += x * x;
    }
#pragma unroll
    for (int off = 32; off; off >>= 1) ss += __shfl_xor(ss, off);
    float scale = 1.0f / fmaxf(sqrtf(ss), 1e-12f);
    _Float16* o = outH + (long)row * KP;
#pragma unroll
    for (int j = 0; j < 5; ++j) {
        int idx = lane + j * 64;
        o[idx] = (_Float16)((idx < E_DIM) ? v[j] * scale : 0.f);
    }
}

// ---------------- Kernel 2: sim GEMM, A+B fully LDS-staged (read-once), swizzled --------
// grid (8, 32) = 256 blocks (1/CU), 512 threads (8 waves: 2 wm x 4 wn). LDS 147.6 KB.
// Each block: A(100x320) + B(125x320) -> sim rows 0..99 x cols ntile*125..+124.
__global__ __launch_bounds__(512, 1) void sim_gemm(const _Float16* __restrict__ wsH,
                                                   _Float16* __restrict__ simW)
{
    __shared__ __align__(16) char Abuf[100 * LDSTB];   // 65600
    __shared__ __align__(16) char Bbuf[125 * LDSTB];   // 82000
    float* simT = (float*)Abuf;                        // overlay after GEMM: 100*132*4 = 52800

    int b = blockIdx.y, ntile = blockIdx.x;
    int tid = threadIdx.x;
    int wave = tid >> 6, lane = tid & 63;
    int wm = wave >> 2, wn = wave & 3;
    int g = lane >> 4, r16 = lane & 15;

    const char* gA = (const char*)(wsH + (size_t)b * 100 * KP);
    const char* gB = (const char*)(wsH + (size_t)(NROW_CDD + b * 1000 + ntile * 125) * KP);

    // stage A: 100 rows x 640 B (4000 uint4), coalesced; XOR-swizzled LDS dest
    for (int u = tid; u < 4000; u += 512) {
        int r = u / 40, c = u - r * 40;
        *(uint4*)(Abuf + ((r * LDSTB + c * 16) ^ ((r & 7) << 4))) = *(const uint4*)(gA + (size_t)u * 16);
    }
    // stage B: 125 rows x 640 B (5000 uint4)
    for (int u = tid; u < 5000; u += 512) {
        int r = u / 40, c = u - r * 40;
        *(uint4*)(Bbuf + ((r * LDSTB + c * 16) ^ ((r & 7) << 4))) = *(const uint4*)(gB + (size_t)u * 16);
    }
    __syncthreads();

    float4v acc[4][2];
#pragma unroll
    for (int m = 0; m < 4; ++m)
#pragma unroll
        for (int n = 0; n < 2; ++n) acc[m][n] = (float4v){0.f, 0.f, 0.f, 0.f};

#pragma unroll 2
    for (int k = 0; k < 10; ++k) {
        half8 bf[2];
#pragma unroll
        for (int n = 0; n < 2; ++n) {
            int rB = wn * 32 + n * 16 + r16; if (rB > 124) rB = 124;
            bf[n] = *(const half8*)(Bbuf + ((rB * LDSTB + k * 64 + g * 16) ^ ((rB & 7) << 4)));
        }
#pragma unroll
        for (int m = 0; m < 4; ++m) {
            int rA = wm * 64 + m * 16 + r16; if (rA > 99) rA = 99;
            half8 af = *(const half8*)(Abuf + ((rA * LDSTB + k * 64 + g * 16) ^ ((rA & 7) << 4)));
#pragma unroll
            for (int n = 0; n < 2; ++n)
                acc[m][n] = __builtin_amdgcn_mfma_f32_16x16x32_f16(af, bf[n], acc[m][n], 0, 0, 0);
        }
    }
    __syncthreads();   // all waves done reading Abuf before overlay

    // C/D layout (validated r1-r7): col = lane&15 (B-row), row = (lane>>4)*4+j (A-row)
#pragma unroll
    for (int m = 0; m < 4; ++m) {
        int rowb = wm * 64 + m * 16 + g * 4;
#pragma unroll
        for (int n = 0; n < 2; ++n) {
            int col = wn * 32 + n * 16 + r16;
            if (col < 125) {
#pragma unroll
                for (int j = 0; j < 4; ++j) {
                    int r = rowb + j;
                    if (r < 100) simT[r * 132 + col] = acc[m][n][j];
                }
            }
        }
    }
    __syncthreads();

    // coalesced fp16 write-out: 100 rows x 125 cols
    size_t obase = (size_t)b * 100000 + (size_t)ntile * 125;
    for (int u = tid; u < 12500; u += 512) {
        int r = u / 125, c = u - r * 125;
        simW[obase + (size_t)r * 1000 + c] = (_Float16)simT[r * 132 + c];
    }
}

// ---------------- Kernel 3: gaussian kernels + log pooling, one block per sim row -------
// grid 3200, 256 threads (250 active: h=tid%50, kq=tid/50, 4 k's each). LDS 12.6 KB.
__global__ __launch_bounds__(256) void knrm_pool(const _Float16* __restrict__ simW,
                                                 const float* __restrict__ cpad,
                                                 const float* __restrict__ hpad,
                                                 const float* __restrict__ ltr_w,
                                                 float* __restrict__ rowsum)
{
    __shared__ float sS[50 * 21];
    __shared__ float mS[50 * 21];
    __shared__ float wS[1000];
    __shared__ float part[4];

    int row = blockIdx.x;            // (b*5+c)*20 + s
    int b = row / 100;
    int tid = threadIdx.x;

    if (tid < 250) {
        int p = tid * 4;
        half4v hv = *(const half4v*)(simW + (size_t)row * 1000 + p);
        float4v mv = *(const float4v*)(hpad + (size_t)b * 1000 + p);
        *(float4v*)&wS[p] = *(const float4v*)(ltr_w + p);
#pragma unroll
        for (int q = 0; q < 4; ++q) {
            int pq = p + q, h = pq / 20, t = pq - h * 20;
            sS[h * 21 + t] = (float)hv[q];
            mS[h * 21 + t] = mv[q];
        }
    }
    __syncthreads();

    float val = 0.f;
    if (tid < 250) {
        int h = tid % 50, kq = tid / 50;     // kq 0..4, k = kq*4+j
        float bj[4], cj[4];
        bool is19[4];
#pragma unroll
        for (int j = 0; j < 4; ++j) {
            float mu = -0.9f + 0.1f * (float)(kq * 4 + j);
            bj[j] = 100.0f * mu;
            cj[j] = -50.0f * mu * mu;
            is19[j] = (kq * 4 + j) == 19;
        }
        float psum0 = 0.f, psum1 = 0.f, psum2 = 0.f, psum3 = 0.f;
        const float* sp = sS + h * 21;
        const float* mp = mS + h * 21;
#pragma unroll 4
        for (int t = 0; t < 20; ++t) {
            float s  = sp[t];
            float mm = mp[t];
            float d  = s - 1.0f;
            float arg19 = -500000.0f * d * d;
            float a0 = is19[0] ? arg19 : fmaf(fmaf(-50.0f, s, bj[0]), s, cj[0]);
            float a1 = is19[1] ? arg19 : fmaf(fmaf(-50.0f, s, bj[1]), s, cj[1]);
            float a2 = is19[2] ? arg19 : fmaf(fmaf(-50.0f, s, bj[2]), s, cj[2]);
            float a3 = is19[3] ? arg19 : fmaf(fmaf(-50.0f, s, bj[3]), s, cj[3]);
            psum0 = fmaf(__expf(a0), mm, psum0);
            psum1 = fmaf(__expf(a1), mm, psum1);
            psum2 = fmaf(__expf(a2), mm, psum2);
            psum3 = fmaf(__expf(a3), mm, psum3);
        }
        const float* wp = wS + h * 20 + kq * 4;
        val  = __logf(fmaxf(psum0, 1e-10f)) * wp[0];
        val += __logf(fmaxf(psum1, 1e-10f)) * wp[1];
        val += __logf(fmaxf(psum2, 1e-10f)) * wp[2];
        val += __logf(fmaxf(psum3, 1e-10f)) * wp[3];
    }
#pragma unroll
    for (int off = 32; off; off >>= 1) val += __shfl_down(val, off);
    int wave = tid >> 6, lane = tid & 63;
    if (lane == 0) part[wave] = val;
    __syncthreads();
    if (tid == 0)
        rowsum[row] = (part[0] + part[1] + part[2] + part[3]) * 0.01f * cpad[row];
}

// ---------------- Kernel 4: sum rows per (b,c) + bias + log_softmax over C=5 ------------
__global__ __launch_bounds__(64) void finalize(const float* __restrict__ rowsum,
                                               const float* __restrict__ ltr_b,
                                               float* __restrict__ out)
{
    int b = blockIdx.x;
    int tid = threadIdx.x;
    __shared__ float sc[5];
    if (tid < 5) {
        float a = ltr_b[0];
        const float* rp = rowsum + (b * 5 + tid) * 20;
#pragma unroll
        for (int s = 0; s < 20; ++s) a += rp[s];
        sc[tid] = a;
    }
    __syncthreads();
    if (tid < 5) {
        float m = fmaxf(fmaxf(fmaxf(sc[0], sc[1]), fmaxf(sc[2], sc[3])), sc[4]);
        float sum = 0.f;
#pragma unroll
        for (int i = 0; i < 5; ++i) sum += __expf(sc[i] - m);
        out[b * 5 + tid] = sc[tid] - m - __logf(sum);
    }
}

extern "C" void kernel_launch(void* const* d_in, const int* in_sizes, int n_in,
                              void* d_out, int out_size, void* d_ws, size_t ws_size,
                              hipStream_t stream)
{
    const int*   cand = (const int*)d_in[0];
    const int*   clk  = (const int*)d_in[1];
    const float* cpad = (const float*)d_in[2];
    const float* hpad = (const float*)d_in[3];
    const float* emb  = (const float*)d_in[4];
    const float* lw   = (const float*)d_in[5];
    const float* lb   = (const float*)d_in[6];
    float* out = (float*)d_out;

    _Float16* wsH  = (_Float16*)d_ws;                                                   // 22.528 MB
    _Float16* simW = (_Float16*)((char*)d_ws + (size_t)(NROW_CDD + NROW_HIS) * KP * 2); // 6.4 MB
    float* rowsum  = (float*)((char*)simW + (size_t)B_ * 100 * 1000 * 2);               // 12.8 KB

    hipLaunchKernelGGL(gather_norm, dim3((NROW_CDD + NROW_HIS) / 4), dim3(256), 0, stream,
                       cand, clk, emb, wsH);
    hipLaunchKernelGGL(sim_gemm, dim3(8, B_), dim3(512), 0, stream, wsH, simW);
    hipLaunchKernelGGL(knrm_pool, dim3(NROW_CDD), dim3(256), 0, stream,
                       simW, cpad, hpad, lw, rowsum);
    hipLaunchKernelGGL(finalize, dim3(B_), dim3(64), 0, stream, rowsum, lb, out);
}